// Round 12
// baseline (489.243 us; speedup 1.0000x reference)
//
#include <hip/hip_runtime.h>

#define NVEC 131072          // 32*64*64 vectors
#define KC 512               // codebook size
#define DD 64                // code dim
#define QOUT_OFF 1
#define PERP_OFF 8388609
#define ENC_OFF  8388610     // even -> float2-aligned
#define TK 64                // codes per pass
#define NPASS 8
#define MBLK 128             // vectors per block
#define NBLK 1024            // NVEC / MBLK

// ws: [0,2048) wnorm | [2048,4096) hist | [4096,12288) partials (2048 f32)

// ---- init: codebook norms (EXACT passing chain order) + zero hist ----
__global__ void vq_init(const float* __restrict__ w, float* __restrict__ wnorm,
                        unsigned int* __restrict__ hist) {
    int k = blockIdx.x * 256 + threadIdx.x;   // 0..511
    const float4* wr = (const float4*)(w + k * DD);
    float4 v[16];
#pragma unroll
    for (int i = 0; i < 16; ++i) v[i] = wr[i];
    float s = 0.f;
#pragma unroll
    for (int i = 0; i < 16; ++i) {            // d-ascending single chain
        s = fmaf(v[i].x, v[i].x, s);
        s = fmaf(v[i].y, v[i].y, s);
        s = fmaf(v[i].z, v[i].z, s);
        s = fmaf(v[i].w, v[i].w, s);
    }
    wnorm[k] = s;
    hist[k] = 0u;
}

// ---- main: 8m x 8k GEMM tile (16 FMA per ds_read_b128 — r11 was 8:1 and
// LDS-pipe-bound at ~164us = 32768 instr x 12cyc). 128 thr = 16mg x 8kg.
__global__ __launch_bounds__(128, 2) void vq_main(
    const float* __restrict__ x, const float* __restrict__ w,
    const float* __restrict__ wnorm, float* __restrict__ out,
    unsigned int* __restrict__ hist, float* __restrict__ partials) {
    __shared__ float  lxT[DD][MBLK];   // 32 KB [d][m]
    __shared__ float4 lw4[TK][16];     // 16 KB [k][chunk ^ (k>>3)]
    __shared__ float  lnorm[KC];       // 2 KB
    __shared__ float  sxx[MBLK];       // 0.5 KB
    __shared__ int    sbid[MBLK];      // 0.5 KB

    const int tid = threadIdx.x;
    const int kg = tid & 7, mg = tid >> 3;
    const int n_base = blockIdx.x * MBLK;
    const int b = n_base >> 12;        // 128 | 4096 -> no image straddle
    const int hw0 = n_base & 4095;

    // stage x-tile transposed [d][m]; global float4-coalesced
    {
        const float4* xg = (const float4*)(x + ((size_t)b << 18) + hw0);
#pragma unroll
        for (int it = 0; it < 16; ++it) {
            int j = it * 128 + tid;            // 0..2047
            int d = j >> 5, m4 = j & 31;
            *(float4*)&lxT[d][m4 * 4] = xg[((size_t)d << 10) + m4];  // 8 touch/quad
        }
    }
    lnorm[tid]       = wnorm[tid];
    lnorm[tid + 128] = wnorm[tid + 128];
    lnorm[tid + 256] = wnorm[tid + 256];
    lnorm[tid + 384] = wnorm[tid + 384];
    __syncthreads();

    // ||x||^2 of own vector: 4 chains by d%4 (== all passing rounds)
    {
        float c0 = 0.f, c1 = 0.f, c2 = 0.f, c3 = 0.f;
#pragma unroll
        for (int d = 0; d < DD; d += 4) {
            float v0 = lxT[d][tid],     v1 = lxT[d + 1][tid];
            float v2 = lxT[d + 2][tid], v3 = lxT[d + 3][tid];
            c0 = fmaf(v0, v0, c0); c1 = fmaf(v1, v1, c1);
            c2 = fmaf(v2, v2, c2); c3 = fmaf(v3, v3, c3);
        }
        sxx[tid] = (c0 + c1) + (c2 + c3);
    }
    __syncthreads();

    float xxr[8];
    {
        float4 a4 = *(const float4*)&sxx[mg * 8];
        float4 b4 = *(const float4*)&sxx[mg * 8 + 4];
        xxr[0] = a4.x; xxr[1] = a4.y; xxr[2] = a4.z; xxr[3] = a4.w;
        xxr[4] = b4.x; xxr[5] = b4.y; xxr[6] = b4.z; xxr[7] = b4.w;
    }

    // encodings zero-fill: 256 float2/thread, 2 per dc-step, overlaps compute
    const float2 z2 = make_float2(0.f, 0.f);
    float2* encb = (float2*)(out + ENC_OFF) + ((size_t)blockIdx.x << 15);

    float best[8]; int bid[8];
#pragma unroll
    for (int j = 0; j < 8; ++j) { best[j] = 3.402823466e38f; bid[j] = 0; }

    for (int p = 0; p < NPASS; ++p) {
        // stage w-tile swizzled: write quads = (dc^(k>>3))&7 -> 8 touch/quad
#pragma unroll
        for (int r = 0; r < 8; ++r) {
            int j = r * 128 + tid;             // 0..1023
            int k = j >> 4, dc = j & 15;
            lw4[k][dc ^ (k >> 3)] = ((const float4*)w)[(p << 10) + j];
        }
        __syncthreads();

        float acc[8][8];
#pragma unroll
        for (int j = 0; j < 8; ++j)
#pragma unroll
            for (int i = 0; i < 8; ++i) acc[j][i] = 0.f;

#pragma unroll 2
        for (int dc = 0; dc < 16; ++dc) {
            encb[(size_t)(p * 16 + dc) * 256 + tid] = z2;
            encb[(size_t)(p * 16 + dc) * 256 + 128 + tid] = z2;
            float4 xf[8];   // [c*2+h]: dims dc*4+c, vectors mg*8+h*4..+3
#pragma unroll
            for (int c = 0; c < 4; ++c) {
                xf[c * 2]     = *(const float4*)&lxT[dc * 4 + c][mg * 8];
                xf[c * 2 + 1] = *(const float4*)&lxT[dc * 4 + c][mg * 8 + 4];
            }
            const int ch = dc ^ kg;            // read quads: 8 distinct across kg
#pragma unroll
            for (int i = 0; i < 8; ++i) {
                const float4 wv = lw4[kg * 8 + i][ch];
#pragma unroll
                for (int j = 0; j < 8; ++j) {
                    const float* x0 = (const float*)&xf[(j >> 2)];
                    const float* x1 = (const float*)&xf[2 + (j >> 2)];
                    const float* x2 = (const float*)&xf[4 + (j >> 2)];
                    const float* x3 = (const float*)&xf[6 + (j >> 2)];
                    float t = acc[j][i];       // d-ascending sequential chain
                    t = fmaf(x0[j & 3], wv.x, t);
                    t = fmaf(x1[j & 3], wv.y, t);
                    t = fmaf(x2[j & 3], wv.z, t);
                    t = fmaf(x3[j & 3], wv.w, t);
                    acc[j][i] = t;
                }
            }
        }

        float4 lnA = *(const float4*)&lnorm[p * 64 + kg * 8];
        float4 lnB = *(const float4*)&lnorm[p * 64 + kg * 8 + 4];
        float lnv[8] = {lnA.x, lnA.y, lnA.z, lnA.w, lnB.x, lnB.y, lnB.z, lnB.w};
#pragma unroll
        for (int j = 0; j < 8; ++j)
#pragma unroll
            for (int i = 0; i < 8; ++i) {      // k = p*64+kg*8+i ascending
                float s = fmaf(-2.0f, acc[j][i], xxr[j] + lnv[i]);  // == passing form
                if (s < best[j]) { best[j] = s; bid[j] = p * 64 + kg * 8 + i; }
            }
        __syncthreads();   // before next pass overwrites lw4
    }

    // cross-lane argmin over 8 kg lanes (lane bits 0-2), ties -> lower k
#pragma unroll
    for (int mask = 1; mask <= 4; mask <<= 1)
#pragma unroll
        for (int j = 0; j < 8; ++j) {
            float ov = __shfl_xor(best[j], mask);
            int oi = __shfl_xor(bid[j], mask);
            if (ov < best[j] || (ov == best[j] && oi < bid[j])) { best[j] = ov; bid[j] = oi; }
        }
    if (kg == 0) {
#pragma unroll
        for (int j = 0; j < 8; ++j) sbid[mg * 8 + j] = bid[j];
    }
    __syncthreads();

    // epilogue: thread owns vector n_base+tid entirely
    const int bidx = sbid[tid];
    atomicAdd(&hist[bidx], 1u);
    float* qo = out + QOUT_OFF + ((size_t)b << 18) + hw0 + tid;
    const float4* wrow = (const float4*)(w + (bidx << 6));   // L2-hot gather
    float ls0 = 0.f, ls1 = 0.f, ls2 = 0.f, ls3 = 0.f;
#pragma unroll
    for (int i = 0; i < 16; ++i) {
        float4 qv = wrow[i];
        int d = i * 4;
        float d0 = qv.x - lxT[d][tid],     d1 = qv.y - lxT[d + 1][tid];
        float d2 = qv.z - lxT[d + 2][tid], d3 = qv.w - lxT[d + 3][tid];
        ls0 = fmaf(d0, d0, ls0); ls1 = fmaf(d1, d1, ls1);
        ls2 = fmaf(d2, d2, ls2); ls3 = fmaf(d3, d3, ls3);
        qo[(size_t)(d) << 12]     = qv.x;   // wave: 256B contiguous per instr
        qo[(size_t)(d + 1) << 12] = qv.y;
        qo[(size_t)(d + 2) << 12] = qv.z;
        qo[(size_t)(d + 3) << 12] = qv.w;
    }
    float ls = (ls0 + ls1) + (ls2 + ls3);
#pragma unroll
    for (int off = 32; off > 0; off >>= 1) ls += __shfl_down(ls, off);
    if ((tid & 63) == 0) partials[blockIdx.x * 2 + (tid >> 6)] = ls;

    // one-hot; prior barriers drained all of this block's zero stores
    __syncthreads();
    out[ENC_OFF + ((size_t)(n_base + tid) << 9) + bidx] = 1.0f;
}

// ---- final: loss scale + perplexity ----
__global__ void vq_final(const unsigned int* __restrict__ hist,
                         const float* __restrict__ partials,
                         float* __restrict__ out) {
    __shared__ float rede[KC];
    __shared__ float redl[KC];
    int k = threadIdx.x;  // 512
    float p = (float)hist[k] * (1.0f / (float)NVEC);
    rede[k] = p * logf(p + 1e-10f);
    float l = 0.f;
#pragma unroll
    for (int i = 0; i < 4; ++i) l += partials[k * 4 + i];
    redl[k] = l;
    __syncthreads();
    for (int s = KC / 2; s > 0; s >>= 1) {
        if (k < s) { rede[k] += rede[k + s]; redl[k] += redl[k + s]; }
        __syncthreads();
    }
    if (k == 0) {
        out[PERP_OFF] = expf(-rede[0]);
        out[0] = 1.25f * redl[0] * (1.0f / 8388608.0f);
    }
}

extern "C" void kernel_launch(void* const* d_in, const int* in_sizes, int n_in,
                              void* d_out, int out_size, void* d_ws, size_t ws_size,
                              hipStream_t stream) {
    const float* x = (const float*)d_in[0];
    const float* w = (const float*)d_in[1];
    float* out = (float*)d_out;

    float* wnorm       = (float*)d_ws;
    unsigned int* hist = (unsigned int*)((char*)d_ws + 2048);
    float* partials    = (float*)((char*)d_ws + 4096);   // 2048 floats

    vq_init<<<2, 256, 0, stream>>>(w, wnorm, hist);
    vq_main<<<NBLK, 128, 0, stream>>>(x, w, wnorm, out, hist, partials);
    vq_final<<<1, KC, 0, stream>>>(hist, partials, out);
}